// Round 6
// baseline (107.444 us; speedup 1.0000x reference)
//
#include <hip/hip_runtime.h>

typedef unsigned short u16;
typedef unsigned int u32;
typedef __attribute__((ext_vector_type(8))) short short8;
typedef __attribute__((ext_vector_type(4))) float f32x4;
typedef __attribute__((ext_vector_type(4))) unsigned short u16x4;
typedef __attribute__((ext_vector_type(2))) unsigned int u32x2;

#define MFMA16(a,b,c) __builtin_amdgcn_mfma_f32_16x16x32_bf16((a),(b),(c),0,0,0)
#define AS3(p) ((__attribute__((address_space(3))) void*)(p))
#define AS1(p) ((const __attribute__((address_space(1))) void*)(p))

__device__ __forceinline__ u16 f2bf(float x){
  union { float f; unsigned u; } un; un.f = x;
  unsigned r = un.u + 0x7fffu + ((un.u >> 16) & 1u);
  return (u16)(r >> 16);
}

// ---------------- f32 -> bf16 convert (both activation tensors, one dispatch) ----------------
__global__ __launch_bounds__(256) void cvt2(const float* __restrict__ q, const float* __restrict__ kv,
                                            u16* __restrict__ oq, u16* __restrict__ okv){
  int bi = blockIdx.x;
  const float* in = (bi < 8192) ? q : kv;
  u16* out = (bi < 8192) ? oq : okv;
  int i = ((bi & 8191) * 256 + threadIdx.x) * 4;
  f32x4 v = *(const f32x4*)(in + i);
  u16x4 r = { f2bf(v[0]), f2bf(v[1]), f2bf(v[2]), f2bf(v[3]) };
  *(u16x4*)(out + i) = r;
}

// ---------------- weight transpose+convert: out[n][k] = in[k][n], 512x512 ----------------
__global__ __launch_bounds__(256) void wtrans(const float* __restrict__ W0, const float* __restrict__ W1,
                                              const float* __restrict__ W2, const float* __restrict__ W3,
                                              u16* __restrict__ out){
  __shared__ float tile[32][33];
  const float* src = (blockIdx.z == 0) ? W0 : (blockIdx.z == 1) ? W1 : (blockIdx.z == 2) ? W2 : W3;
  u16* dst = out + (size_t)blockIdx.z * 262144;
  int k0 = blockIdx.x * 32, n0 = blockIdx.y * 32;
  int tx = threadIdx.x, ty = threadIdx.y;
  #pragma unroll
  for (int i = 0; i < 4; ++i)
    tile[ty + 8*i][tx] = src[(size_t)(k0 + ty + 8*i)*512 + n0 + tx];
  __syncthreads();
  #pragma unroll
  for (int i = 0; i < 4; ++i)
    dst[(size_t)(n0 + ty + 8*i)*512 + k0 + tx] = f2bf(tile[tx][ty + 8*i]);
}

// ---------------- shared GEMM core (all-bf16 operands, async LDS staging) ----------------
// LDS bytes: A bufs [0,16384) (2 x 8KB), B bufs [16384,32768). Rows 64 B, 16B chunks
// XOR-swizzled by ((row>>1)&3)<<4 via pre-swizzled global source (rule 21).
// MODE 0: bf16 out -> [B,H,S,D]; MODE 2: bf16 out -> vT[(b*512+col)*8192+s]; MODE 1: f32 row-major.
template<int MODE>
__device__ __forceinline__ void gemm_core(u16* sm, const u16* __restrict__ A, const u16* __restrict__ BT,
                                          const float* __restrict__ bias,
                                          u16* __restrict__ outb, float* __restrict__ outf,
                                          int bm, int bn){
  const int tid = threadIdx.x, lane = tid & 63, w = tid >> 6;
  const int g = lane >> 4, c = lane & 15;
  const int wm = (w >> 1) * 64, wn = (w & 1) * 64;
  f32x4 acc[4][4];
  #pragma unroll
  for (int mi = 0; mi < 4; ++mi)
    #pragma unroll
    for (int ni = 0; ni < 4; ++ni){ f32x4 z = {0.f,0.f,0.f,0.f}; acc[mi][ni] = z; }

  auto stageA = [&](int buf, int kt){
    #pragma unroll
    for (int j = 0; j < 2; ++j){
      int lrow = 32*w + 16*j;
      int row = lrow + (lane >> 2), f = (row >> 1) & 3;
      const u16* ga = A + (size_t)(bm*128 + row)*512 + kt*32 + ((lane & 3) ^ f)*8;
      __builtin_amdgcn_global_load_lds(AS1(ga), AS3(sm + buf*4096 + lrow*32), 16, 0, 0);
    }
  };
  auto stageB = [&](int buf, int kt){
    #pragma unroll
    for (int j = 0; j < 2; ++j){
      int lrow = 32*w + 16*j;
      int row = lrow + (lane >> 2), f = (row >> 1) & 3;
      const u16* gb = BT + (size_t)(bn*128 + row)*512 + kt*32 + ((lane & 3) ^ f)*8;
      __builtin_amdgcn_global_load_lds(AS1(gb), AS3(sm + 8192 + buf*4096 + lrow*32), 16, 0, 0);
    }
  };
  auto compute = [&](int buf){
    short8 af[4], bfv[4];
    #pragma unroll
    for (int i = 0; i < 4; ++i){
      int ra = wm + 16*i + c;
      af[i]  = *(const short8*)((char*)sm + buf*8192 + ra*64 + ((g*16) ^ (((ra >> 1) & 3) << 4)));
      int rb = wn + 16*i + c;
      bfv[i] = *(const short8*)((char*)sm + 16384 + buf*8192 + rb*64 + ((g*16) ^ (((rb >> 1) & 3) << 4)));
    }
    #pragma unroll
    for (int mi = 0; mi < 4; ++mi)
      #pragma unroll
      for (int ni = 0; ni < 4; ++ni)
        acc[mi][ni] = MFMA16(af[mi], bfv[ni], acc[mi][ni]);
  };

  stageA(0, 0); stageB(0, 0);
  int buf = 0;
  for (int kt = 0; kt < 16; ++kt){
    __syncthreads();                       // drains stage into sm[buf]
    if (kt < 15){ stageA(buf ^ 1, kt + 1); stageB(buf ^ 1, kt + 1); }
    compute(buf);
    buf ^= 1;
  }
  __syncthreads();   // staging dead; sm reused as epilogue repack tile

  const int lane3 = tid & 7;
  if (MODE == 0){
    #pragma unroll
    for (int mi = 0; mi < 4; ++mi)
      #pragma unroll
      for (int ni = 0; ni < 4; ++ni){
        int colL = wn + 16*ni + c;
        float bv = bias[bn*128 + colL];
        #pragma unroll
        for (int r = 0; r < 4; ++r){
          int rowL = wm + 16*mi + 4*g + r;
          int byt = rowL*256 + ((colL*2) ^ ((rowL & 7) << 4));
          *(u16*)((char*)sm + byt) = f2bf(acc[mi][ni][r] + bv);
        }
      }
    __syncthreads();
    #pragma unroll
    for (int p = 0; p < 8; ++p){
      int rh = (tid >> 3) + p*32;
      int rowL = rh >> 1, half = rh & 1;
      int byt = rowL*256 + ((half*128 + lane3*16) ^ ((rowL & 7) << 4));
      short8 vdat = *(const short8*)((char*)sm + byt);
      int rowG = bm*128 + rowL;
      int bb = rowG >> 13, s = rowG & 8191;
      int hh = bn*2 + half;
      *(short8*)(outb + (((size_t)(bb*8 + hh)*8192 + s) << 6) + lane3*8) = vdat;
    }
  } else if (MODE == 2){
    #pragma unroll
    for (int mi = 0; mi < 4; ++mi)
      #pragma unroll
      for (int ni = 0; ni < 4; ++ni){
        int colL = wn + 16*ni + c;
        float bv = bias[bn*128 + colL];
        u16x4 pk = { f2bf(acc[mi][ni][0] + bv), f2bf(acc[mi][ni][1] + bv),
                     f2bf(acc[mi][ni][2] + bv), f2bf(acc[mi][ni][3] + bv) };
        int row0 = wm + 16*mi + 4*g;
        int byt = colL*256 + ((row0*2) ^ ((colL & 7) << 4));
        *(u16x4*)((char*)sm + byt) = pk;
      }
    __syncthreads();
    #pragma unroll
    for (int p = 0; p < 8; ++p){
      int rh = (tid >> 3) + p*32;
      int colL = rh >> 1, half = rh & 1;
      int byt = colL*256 + ((half*128 + lane3*16) ^ ((colL & 7) << 4));
      short8 vdat = *(const short8*)((char*)sm + byt);
      int rowG0 = bm*128 + half*64 + lane3*8;
      int bb = rowG0 >> 13, s = rowG0 & 8191;
      int colG = bn*128 + colL;
      *(short8*)(outb + (((size_t)(bb*512 + colG)) << 13) + s) = vdat;
    }
  } else {
    // f32 out via two 64-row LDS repack phases
    float* smf = (float*)sm;
    #pragma unroll
    for (int hh = 0; hh < 2; ++hh){
      if ((w >> 1) == hh){
        #pragma unroll
        for (int mi = 0; mi < 4; ++mi)
          #pragma unroll
          for (int ni = 0; ni < 4; ++ni){
            int colL = wn + 16*ni + c;
            float bv = bias[bn*128 + colL];
            #pragma unroll
            for (int r = 0; r < 4; ++r){
              int rowh = 16*mi + 4*g + r;
              int byt = rowh*512 + ((colL*4) ^ (((rowh >> 2) & 7) << 4));
              *(float*)((char*)smf + byt) = acc[mi][ni][r] + bv;
            }
          }
      }
      __syncthreads();
      #pragma unroll
      for (int p = 0; p < 8; ++p){
        int idx = p*256 + tid;
        int row = idx >> 5, chunk = idx & 31;
        int byt = row*512 + ((chunk*16) ^ (((row >> 2) & 7) << 4));
        f32x4 vdat = *(const f32x4*)((char*)smf + byt);
        *(f32x4*)(outf + (size_t)(bm*128 + hh*64 + row)*512 + bn*128 + chunk*4) = vdat;
      }
      __syncthreads();
    }
  }
}

// merged QKV projection (bf16 A), 1D grid 1536, XCD-chunked, bn fastest in-chunk
__global__ __launch_bounds__(256, 4) void gemm_qkv(const u16* __restrict__ Xq, const u16* __restrict__ Xkv,
                                                   const u16* __restrict__ wT,
                                                   const float* __restrict__ bq, const float* __restrict__ bk,
                                                   const float* __restrict__ bv,
                                                   u16* __restrict__ qb, u16* __restrict__ kbf, u16* __restrict__ vT){
  __shared__ u16 sm[16384];
  int bi = blockIdx.x;
  int orig = (bi & 7)*192 + (bi >> 3);
  int bm = orig / 12, bn = orig % 12;
  int which = bn >> 2, bnn = bn & 3;
  const u16* A = which ? Xkv : Xq;
  const u16* BT = wT + which*262144;
  const float* bias = (which == 0) ? bq : (which == 1) ? bk : bv;
  if (which == 2) gemm_core<2>(sm, A, BT, bias, vT, nullptr, bm, bnn);
  else            gemm_core<0>(sm, A, BT, bias, (which == 0) ? qb : kbf, nullptr, bm, bnn);
}

// output projection: 1D grid 512, XCD-chunked; bf16 A, f32 out
__global__ __launch_bounds__(256, 4) void gemm_out(const u16* __restrict__ A, const u16* __restrict__ BT,
                                                   const float* __restrict__ bias, float* __restrict__ outf){
  __shared__ u16 sm[16384];
  int bi = blockIdx.x;
  int orig = (bi & 7)*64 + (bi >> 3);
  int bm = orig >> 2, bn = orig & 3;
  gemm_core<1>(sm, A, BT, bias, nullptr, outf, bm, bn);
}

// ---------------- banded flash attention, 8 waves x 16 q-rows ----------------
// 1D grid 1024, XCD-chunked (adjacent n co-XCD for K/V L2 reuse)
__global__ __launch_bounds__(512, 4) void attn8(const u16* __restrict__ Qg, const u16* __restrict__ Kg,
                                                const u16* __restrict__ VTg, u16* __restrict__ Og){
  __shared__ u16 lK[128*64];
  __shared__ u16 lVT[64*128];
  __shared__ u16 lP[128*128];
  const int tid = threadIdx.x, lane = tid & 63, w = tid >> 6;
  const int g = lane >> 4, c = lane & 15;
  int bi = blockIdx.x;
  int orig = (bi & 7)*128 + (bi >> 3);
  const int n = orig & 63, h = (orig >> 6) & 7, b = orig >> 9;
  const size_t baseq = ((size_t)(b*8 + h)) << 19;
  const size_t basev = ((size_t)((b*8 + h)*64)) << 13;

  short8 qf0, qf1;
  {
    const u16* qp = Qg + baseq + (size_t)(n*128 + w*16 + c)*64 + g*8;
    qf0 = *(const short8*)qp;
    qf1 = *(const short8*)(qp + 32);
  }

  float m_run = -1e30f, l_run = 0.f;
  f32x4 oacc[4];
  #pragma unroll
  for (int dn = 0; dn < 4; ++dn){ f32x4 z = {0.f,0.f,0.f,0.f}; oacc[dn] = z; }

  const int lo = (n == 0) ? 1 : 0;
  const int hi = (n == 63) ? 1 : 2;

  const int sr = tid >> 2, sq = tid & 3;
  const int vd = tid >> 3, vc = tid & 7;

  short8 kr0, kr1, vr0, vr1;
  {
    int kstart = n*128 + (lo - 1)*128;
    const u16* kp = Kg + baseq + (size_t)(kstart + sr)*64 + sq*16;
    kr0 = *(const short8*)kp; kr1 = *(const short8*)(kp + 8);
    const u16* vp = VTg + basev + ((size_t)vd << 13) + kstart + vc*16;
    vr0 = *(const short8*)vp; vr1 = *(const short8*)(vp + 8);
  }

  const int prow = w*16 + c;
  const float SCL = 0.125f * 1.44269504f;

  for (int kb = lo; kb <= hi; ++kb){
    {
      int byt = sr*128 + ((sq*32) ^ ((sr & 7) << 4));
      *(short8*)((char*)lK + byt) = kr0;
      byt = sr*128 + ((sq*32 + 16) ^ ((sr & 7) << 4));
      *(short8*)((char*)lK + byt) = kr1;
      int byt2 = vd*256 + ((vc*32) ^ ((vd & 7) << 4));
      *(short8*)((char*)lVT + byt2) = vr0;
      byt2 = vd*256 + ((vc*32 + 16) ^ ((vd & 7) << 4));
      *(short8*)((char*)lVT + byt2) = vr1;
    }
    __syncthreads();

    if (kb < hi){
      int kstart = n*128 + kb*128;
      const u16* kp = Kg + baseq + (size_t)(kstart + sr)*64 + sq*16;
      kr0 = *(const short8*)kp; kr1 = *(const short8*)(kp + 8);
      const u16* vp = VTg + basev + ((size_t)vd << 13) + kstart + vc*16;
      vr0 = *(const short8*)vp; vr1 = *(const short8*)(vp + 8);
    }

    f32x4 st[8];
    #pragma unroll
    for (int nt = 0; nt < 8; ++nt){ f32x4 z = {0.f,0.f,0.f,0.f}; st[nt] = z; }
    __builtin_amdgcn_s_setprio(1);
    #pragma unroll
    for (int nt = 0; nt < 8; ++nt){
      int row = nt*16 + c;
      int swz = (row & 7) << 4;
      short8 kf0 = *(const short8*)((char*)lK + row*128 + ((g*16) ^ swz));
      short8 kf1 = *(const short8*)((char*)lK + row*128 + ((64 + g*16) ^ swz));
      st[nt] = MFMA16(kf0, qf0, st[nt]);
      st[nt] = MFMA16(kf1, qf1, st[nt]);
    }
    __builtin_amdgcn_s_setprio(0);

    int koff = (kb - 1)*128 - (w*16 + c);
    float mx = -1e30f;
    #pragma unroll
    for (int nt = 0; nt < 8; ++nt)
      #pragma unroll
      for (int r = 0; r < 4; ++r){
        int rel = koff + nt*16 + 4*g + r;
        float s = (rel >= -128 && rel <= 127) ? st[nt][r] * SCL : -1e30f;
        st[nt][r] = s;
        mx = fmaxf(mx, s);
      }
    mx = fmaxf(mx, __shfl_xor(mx, 16));
    mx = fmaxf(mx, __shfl_xor(mx, 32));
    float mnew = fmaxf(m_run, mx);
    float fac = __builtin_amdgcn_exp2f(m_run - mnew);
    m_run = mnew;
    float rs = 0.f;
    #pragma unroll
    for (int nt = 0; nt < 8; ++nt)
      #pragma unroll
      for (int r = 0; r < 4; ++r){
        float p = __builtin_amdgcn_exp2f(st[nt][r] - mnew);
        st[nt][r] = p; rs += p;
      }
    rs += __shfl_xor(rs, 16);
    rs += __shfl_xor(rs, 32);
    l_run = l_run * fac + rs;
    #pragma unroll
    for (int r = 0; r < 4; ++r){
      float fr = __shfl(fac, g*20 + r);
      #pragma unroll
      for (int dn = 0; dn < 4; ++dn) oacc[dn][r] *= fr;
    }

    #pragma unroll
    for (int nt = 0; nt < 8; ++nt){
      u32 plo, phi;
      asm volatile("v_cvt_pk_bf16_f32 %0, %1, %2" : "=v"(plo) : "v"(st[nt][0]), "v"(st[nt][1]));
      asm volatile("v_cvt_pk_bf16_f32 %0, %1, %2" : "=v"(phi) : "v"(st[nt][2]), "v"(st[nt][3]));
      u32x2 pv = { plo, phi };
      int byt = prow*256 + ((nt*32 + g*8) ^ ((c & 7) << 4));
      *(u32x2*)((char*)lP + byt) = pv;
    }

    __builtin_amdgcn_s_setprio(1);
    #pragma unroll
    for (int kt = 0; kt < 4; ++kt){
      short8 pa = *(const short8*)((char*)lP + prow*256 + ((kt*64 + g*16) ^ ((c & 7) << 4)));
      #pragma unroll
      for (int dn = 0; dn < 4; ++dn){
        int dd = dn*16 + c;
        short8 vb = *(const short8*)((char*)lVT + dd*256 + ((kt*64 + g*16) ^ ((c & 7) << 4)));
        oacc[dn] = MFMA16(pa, vb, oacc[dn]);
      }
    }
    __builtin_amdgcn_s_setprio(0);
    __syncthreads();
  }

  #pragma unroll
  for (int r = 0; r < 4; ++r){
    float li = __shfl(l_run, g*20 + r);
    float inv = 1.0f / li;
    size_t orow = ((size_t)(b*8192 + n*128 + w*16 + 4*g + r))*512 + h*64 + c;
    #pragma unroll
    for (int dn = 0; dn < 4; ++dn)
      Og[orow + dn*16] = f2bf(oacc[dn][r] * inv);
  }
}

extern "C" void kernel_launch(void* const* d_in, const int* in_sizes, int n_in,
                              void* d_out, int out_size, void* d_ws, size_t ws_size,
                              hipStream_t stream) {
  const float* inq  = (const float*)d_in[0];
  const float* inkv = (const float*)d_in[1];
  const float* Wq   = (const float*)d_in[2];
  const float* bq   = (const float*)d_in[3];
  const float* Wk   = (const float*)d_in[4];
  const float* bk   = (const float*)d_in[5];
  const float* Wv   = (const float*)d_in[6];
  const float* bv   = (const float*)d_in[7];
  const float* Wo   = (const float*)d_in[8];
  const float* bo   = (const float*)d_in[9];

  // workspace layout (bytes); total 82 MB
  char* ws = (char*)d_ws;
  u16* Xq  = (u16*)(ws + 0);                       // 16 MB  [16384,512] bf16
  u16* Xkv = (u16*)(ws + ((size_t)16 << 20));      // 16 MB
  u16* qb  = (u16*)(ws + ((size_t)32 << 20));      // 16 MB [B,H,S,D]
  u16* kbf = (u16*)(ws + ((size_t)48 << 20));      // 16 MB [B,H,S,D]
  u16* vT  = (u16*)(ws + ((size_t)64 << 20));      // 16 MB [B*H,D,S]
  u16* wT  = (u16*)(ws + ((size_t)80 << 20));      // 2 MB   4x [512,512] bf16 (transposed)
  u16* ob  = (u16*)(ws + 0);                       // reuse Xq slot (dead after gemm_qkv)

  cvt2<<<16384, 256, 0, stream>>>(inq, inkv, Xq, Xkv);
  wtrans<<<dim3(16,16,4), dim3(32,8), 0, stream>>>(Wq, Wk, Wv, Wo, wT);

  gemm_qkv<<<1536, 256, 0, stream>>>(Xq, Xkv, wT, bq, bk, bv, qb, kbf, vT);

  attn8<<<1024, 512, 0, stream>>>(qb, kbf, vT, ob);

  gemm_out<<<512, 256, 0, stream>>>(ob, wT + 3*262144, bo, (float*)d_out);
}

// Round 7
// 102.122 us; speedup vs baseline: 1.0521x; 1.0521x over previous
//
#include <hip/hip_runtime.h>

typedef unsigned short u16;
typedef unsigned int u32;
typedef __attribute__((ext_vector_type(8))) short short8;
typedef __attribute__((ext_vector_type(4))) float f32x4;
typedef __attribute__((ext_vector_type(4))) unsigned short u16x4;
typedef __attribute__((ext_vector_type(2))) unsigned int u32x2;

#define MFMA16(a,b,c) __builtin_amdgcn_mfma_f32_16x16x32_bf16((a),(b),(c),0,0,0)
#define AS3(p) ((__attribute__((address_space(3))) void*)(p))
#define AS1(p) ((const __attribute__((address_space(1))) void*)(p))

__device__ __forceinline__ u16 f2bf(float x){
  union { float f; unsigned u; } un; un.f = x;
  unsigned r = un.u + 0x7fffu + ((un.u >> 16) & 1u);
  return (u16)(r >> 16);
}

// ---------------- merged: weight transpose (blocks 0..1023) + f32->bf16 convert (rest) ----------------
__global__ __launch_bounds__(256) void cvtw(const float* __restrict__ q, const float* __restrict__ kv,
                                            const float* __restrict__ W0, const float* __restrict__ W1,
                                            const float* __restrict__ W2, const float* __restrict__ W3,
                                            u16* __restrict__ oq, u16* __restrict__ okv, u16* __restrict__ wT){
  __shared__ float tile[32][33];
  int bi = blockIdx.x, tid = threadIdx.x;
  if (bi < 1024){
    int z = bi >> 8, rem = bi & 255, bx = rem >> 4, by = rem & 15;
    const float* src = (z == 0) ? W0 : (z == 1) ? W1 : (z == 2) ? W2 : W3;
    u16* dst = wT + (size_t)z * 262144;
    int k0 = bx*32, n0 = by*32, tx = tid & 31, ty = tid >> 5;
    #pragma unroll
    for (int i = 0; i < 4; ++i)
      tile[ty + 8*i][tx] = src[(size_t)(k0 + ty + 8*i)*512 + n0 + tx];
    __syncthreads();
    #pragma unroll
    for (int i = 0; i < 4; ++i)
      dst[(size_t)(n0 + ty + 8*i)*512 + k0 + tx] = f2bf(tile[tx][ty + 8*i]);
  } else {
    int idx = bi - 1024;
    const float* in = (idx < 8192) ? q : kv;
    u16* out = (idx < 8192) ? oq : okv;
    int i = ((idx & 8191) * 256 + tid) * 4;
    f32x4 v = *(const f32x4*)(in + i);
    u16x4 r = { f2bf(v[0]), f2bf(v[1]), f2bf(v[2]), f2bf(v[3]) };
    *(u16x4*)(out + i) = r;
  }
}

// ---------------- shared GEMM core (bf16 operands, ring-3 async staging, counted vmcnt) ----------------
// LDS bytes: A bufs 0..24576 (3 x 8KB), B bufs 24576..49152 (3 x 8KB). Rows 64 B, 16B chunks
// XOR-swizzled by ((row>>1)&3)<<4 via pre-swizzled global source.
// MODE 0: bf16 out -> [B,H,S,D]; MODE 2: bf16 out -> vT[(b*512+col)*8192+s]; MODE 1: f32 row-major.
template<int MODE>
__device__ __forceinline__ void gemm_core(u16* sm, const u16* __restrict__ A, const u16* __restrict__ BT,
                                          const float* __restrict__ bias,
                                          u16* __restrict__ outb, float* __restrict__ outf,
                                          int bm, int bn){
  const int tid = threadIdx.x, lane = tid & 63, w = tid >> 6;
  const int g = lane >> 4, c = lane & 15;
  const int wm = (w >> 1) * 64, wn = (w & 1) * 64;
  f32x4 acc[4][4];
  #pragma unroll
  for (int mi = 0; mi < 4; ++mi)
    #pragma unroll
    for (int ni = 0; ni < 4; ++ni){ f32x4 z = {0.f,0.f,0.f,0.f}; acc[mi][ni] = z; }

  auto stageA = [&](int buf, int kt){
    #pragma unroll
    for (int j = 0; j < 2; ++j){
      int lrow = 32*w + 16*j;
      int row = lrow + (lane >> 2), f = (row >> 1) & 3;
      const u16* ga = A + (size_t)(bm*128 + row)*512 + kt*32 + ((lane & 3) ^ f)*8;
      __builtin_amdgcn_global_load_lds(AS1(ga), AS3(sm + buf*4096 + lrow*32), 16, 0, 0);
    }
  };
  auto stageB = [&](int buf, int kt){
    #pragma unroll
    for (int j = 0; j < 2; ++j){
      int lrow = 32*w + 16*j;
      int row = lrow + (lane >> 2), f = (row >> 1) & 3;
      const u16* gb = BT + (size_t)(bn*128 + row)*512 + kt*32 + ((lane & 3) ^ f)*8;
      __builtin_amdgcn_global_load_lds(AS1(gb), AS3(sm + 12288 + buf*4096 + lrow*32), 16, 0, 0);
    }
  };
  auto compute = [&](int buf){
    short8 af[4], bfv[4];
    #pragma unroll
    for (int i = 0; i < 4; ++i){
      int ra = wm + 16*i + c;
      af[i]  = *(const short8*)((char*)sm + buf*8192 + ra*64 + ((g*16) ^ (((ra >> 1) & 3) << 4)));
      int rb = wn + 16*i + c;
      bfv[i] = *(const short8*)((char*)sm + 24576 + buf*8192 + rb*64 + ((g*16) ^ (((rb >> 1) & 3) << 4)));
    }
    #pragma unroll
    for (int mi = 0; mi < 4; ++mi)
      #pragma unroll
      for (int ni = 0; ni < 4; ++ni)
        acc[mi][ni] = MFMA16(af[mi], bfv[ni], acc[mi][ni]);
  };

  // prologue: stage tiles 0 and 1 (8 loads/wave outstanding)
  stageA(0, 0); stageB(0, 0);
  stageA(1, 1); stageB(1, 1);

  int b0 = 0;
  for (int kt = 0; kt < 16; ++kt){
    // wait only for the OLDEST staged tile (4 loads/wave stay in flight), then sync
    if (kt == 15) { asm volatile("s_waitcnt vmcnt(0)" ::: "memory"); }
    else          { asm volatile("s_waitcnt vmcnt(4)" ::: "memory"); }
    __builtin_amdgcn_sched_barrier(0);
    __builtin_amdgcn_s_barrier();
    __builtin_amdgcn_sched_barrier(0);
    if (kt < 14){
      int b2 = b0 + 2; if (b2 >= 3) b2 -= 3;
      stageA(b2, kt + 2); stageB(b2, kt + 2);
    }
    compute(b0);
    b0 = (b0 == 2) ? 0 : b0 + 1;
  }
  __syncthreads();   // staging dead; sm reused as epilogue repack tile

  const int lane3 = tid & 7;
  if (MODE == 0){
    #pragma unroll
    for (int mi = 0; mi < 4; ++mi)
      #pragma unroll
      for (int ni = 0; ni < 4; ++ni){
        int colL = wn + 16*ni + c;
        float bv = bias[bn*128 + colL];
        #pragma unroll
        for (int r = 0; r < 4; ++r){
          int rowL = wm + 16*mi + 4*g + r;
          int byt = rowL*256 + ((colL*2) ^ ((rowL & 7) << 4));
          *(u16*)((char*)sm + byt) = f2bf(acc[mi][ni][r] + bv);
        }
      }
    __syncthreads();
    #pragma unroll
    for (int p = 0; p < 8; ++p){
      int rh = (tid >> 3) + p*32;
      int rowL = rh >> 1, half = rh & 1;
      int byt = rowL*256 + ((half*128 + lane3*16) ^ ((rowL & 7) << 4));
      short8 vdat = *(const short8*)((char*)sm + byt);
      int rowG = bm*128 + rowL;
      int bb = rowG >> 13, s = rowG & 8191;
      int hh = bn*2 + half;
      *(short8*)(outb + (((size_t)(bb*8 + hh)*8192 + s) << 6) + lane3*8) = vdat;
    }
  } else if (MODE == 2){
    #pragma unroll
    for (int mi = 0; mi < 4; ++mi)
      #pragma unroll
      for (int ni = 0; ni < 4; ++ni){
        int colL = wn + 16*ni + c;
        float bv = bias[bn*128 + colL];
        u16x4 pk = { f2bf(acc[mi][ni][0] + bv), f2bf(acc[mi][ni][1] + bv),
                     f2bf(acc[mi][ni][2] + bv), f2bf(acc[mi][ni][3] + bv) };
        int row0 = wm + 16*mi + 4*g;
        int byt = colL*256 + ((row0*2) ^ ((colL & 7) << 4));
        *(u16x4*)((char*)sm + byt) = pk;
      }
    __syncthreads();
    #pragma unroll
    for (int p = 0; p < 8; ++p){
      int rh = (tid >> 3) + p*32;
      int colL = rh >> 1, half = rh & 1;
      int byt = colL*256 + ((half*128 + lane3*16) ^ ((colL & 7) << 4));
      short8 vdat = *(const short8*)((char*)sm + byt);
      int rowG0 = bm*128 + half*64 + lane3*8;
      int bb = rowG0 >> 13, s = rowG0 & 8191;
      int colG = bn*128 + colL;
      *(short8*)(outb + (((size_t)(bb*512 + colG)) << 13) + s) = vdat;
    }
  } else {
    // f32 out via two 64-row LDS repack phases
    float* smf = (float*)sm;
    #pragma unroll
    for (int hh = 0; hh < 2; ++hh){
      if ((w >> 1) == hh){
        #pragma unroll
        for (int mi = 0; mi < 4; ++mi)
          #pragma unroll
          for (int ni = 0; ni < 4; ++ni){
            int colL = wn + 16*ni + c;
            float bv = bias[bn*128 + colL];
            #pragma unroll
            for (int r = 0; r < 4; ++r){
              int rowh = 16*mi + 4*g + r;
              int byt = rowh*512 + ((colL*4) ^ (((rowh >> 2) & 7) << 4));
              *(float*)((char*)smf + byt) = acc[mi][ni][r] + bv;
            }
          }
      }
      __syncthreads();
      #pragma unroll
      for (int p = 0; p < 8; ++p){
        int idx = p*256 + tid;
        int row = idx >> 5, chunk = idx & 31;
        int byt = row*512 + ((chunk*16) ^ (((row >> 2) & 7) << 4));
        f32x4 vdat = *(const f32x4*)((char*)smf + byt);
        *(f32x4*)(outf + (size_t)(bm*128 + hh*64 + row)*512 + bn*128 + chunk*4) = vdat;
      }
      __syncthreads();
    }
  }
}

// merged QKV projection (bf16 A), 1D grid 1536, XCD-chunked, bn fastest in-chunk
__global__ __launch_bounds__(256, 3) void gemm_qkv(const u16* __restrict__ Xq, const u16* __restrict__ Xkv,
                                                   const u16* __restrict__ wT,
                                                   const float* __restrict__ bq, const float* __restrict__ bk,
                                                   const float* __restrict__ bv,
                                                   u16* __restrict__ qb, u16* __restrict__ kbf, u16* __restrict__ vT){
  __shared__ u16 sm[24576];
  int bi = blockIdx.x;
  int orig = (bi & 7)*192 + (bi >> 3);
  int bm = orig / 12, bn = orig % 12;
  int which = bn >> 2, bnn = bn & 3;
  const u16* A = which ? Xkv : Xq;
  const u16* BT = wT + which*262144;
  const float* bias = (which == 0) ? bq : (which == 1) ? bk : bv;
  if (which == 2) gemm_core<2>(sm, A, BT, bias, vT, nullptr, bm, bnn);
  else            gemm_core<0>(sm, A, BT, bias, (which == 0) ? qb : kbf, nullptr, bm, bnn);
}

// output projection: 1D grid 512, XCD-chunked; bf16 A, f32 out
__global__ __launch_bounds__(256, 3) void gemm_out(const u16* __restrict__ A, const u16* __restrict__ BT,
                                                   const float* __restrict__ bias, float* __restrict__ outf){
  __shared__ u16 sm[24576];
  int bi = blockIdx.x;
  int orig = (bi & 7)*64 + (bi >> 3);
  int bm = orig >> 2, bn = orig & 3;
  gemm_core<1>(sm, A, BT, bias, nullptr, outf, bm, bn);
}

// ---------------- banded flash attention, 8 waves x 16 q-rows ----------------
// 1D grid 1024, XCD-chunked (adjacent n co-XCD for K/V L2 reuse)
__global__ __launch_bounds__(512, 4) void attn8(const u16* __restrict__ Qg, const u16* __restrict__ Kg,
                                                const u16* __restrict__ VTg, u16* __restrict__ Og){
  __shared__ u16 lK[128*64];
  __shared__ u16 lVT[64*128];
  __shared__ u16 lP[128*128];
  const int tid = threadIdx.x, lane = tid & 63, w = tid >> 6;
  const int g = lane >> 4, c = lane & 15;
  int bi = blockIdx.x;
  int orig = (bi & 7)*128 + (bi >> 3);
  const int n = orig & 63, h = (orig >> 6) & 7, b = orig >> 9;
  const size_t baseq = ((size_t)(b*8 + h)) << 19;
  const size_t basev = ((size_t)((b*8 + h)*64)) << 13;

  short8 qf0, qf1;
  {
    const u16* qp = Qg + baseq + (size_t)(n*128 + w*16 + c)*64 + g*8;
    qf0 = *(const short8*)qp;
    qf1 = *(const short8*)(qp + 32);
  }

  float m_run = -1e30f, l_run = 0.f;
  f32x4 oacc[4];
  #pragma unroll
  for (int dn = 0; dn < 4; ++dn){ f32x4 z = {0.f,0.f,0.f,0.f}; oacc[dn] = z; }

  const int lo = (n == 0) ? 1 : 0;
  const int hi = (n == 63) ? 1 : 2;

  const int sr = tid >> 2, sq = tid & 3;
  const int vd = tid >> 3, vc = tid & 7;

  short8 kr0, kr1, vr0, vr1;
  {
    int kstart = n*128 + (lo - 1)*128;
    const u16* kp = Kg + baseq + (size_t)(kstart + sr)*64 + sq*16;
    kr0 = *(const short8*)kp; kr1 = *(const short8*)(kp + 8);
    const u16* vp = VTg + basev + ((size_t)vd << 13) + kstart + vc*16;
    vr0 = *(const short8*)vp; vr1 = *(const short8*)(vp + 8);
  }

  const int prow = w*16 + c;
  const float SCL = 0.125f * 1.44269504f;

  for (int kb = lo; kb <= hi; ++kb){
    {
      int byt = sr*128 + ((sq*32) ^ ((sr & 7) << 4));
      *(short8*)((char*)lK + byt) = kr0;
      byt = sr*128 + ((sq*32 + 16) ^ ((sr & 7) << 4));
      *(short8*)((char*)lK + byt) = kr1;
      int byt2 = vd*256 + ((vc*32) ^ ((vd & 7) << 4));
      *(short8*)((char*)lVT + byt2) = vr0;
      byt2 = vd*256 + ((vc*32 + 16) ^ ((vd & 7) << 4));
      *(short8*)((char*)lVT + byt2) = vr1;
    }
    __syncthreads();

    if (kb < hi){
      int kstart = n*128 + kb*128;
      const u16* kp = Kg + baseq + (size_t)(kstart + sr)*64 + sq*16;
      kr0 = *(const short8*)kp; kr1 = *(const short8*)(kp + 8);
      const u16* vp = VTg + basev + ((size_t)vd << 13) + kstart + vc*16;
      vr0 = *(const short8*)vp; vr1 = *(const short8*)(vp + 8);
    }

    f32x4 st[8];
    #pragma unroll
    for (int nt = 0; nt < 8; ++nt){ f32x4 z = {0.f,0.f,0.f,0.f}; st[nt] = z; }
    __builtin_amdgcn_s_setprio(1);
    #pragma unroll
    for (int nt = 0; nt < 8; ++nt){
      int row = nt*16 + c;
      int swz = (row & 7) << 4;
      short8 kf0 = *(const short8*)((char*)lK + row*128 + ((g*16) ^ swz));
      short8 kf1 = *(const short8*)((char*)lK + row*128 + ((64 + g*16) ^ swz));
      st[nt] = MFMA16(kf0, qf0, st[nt]);
      st[nt] = MFMA16(kf1, qf1, st[nt]);
    }
    __builtin_amdgcn_s_setprio(0);

    int koff = (kb - 1)*128 - (w*16 + c);
    float mx = -1e30f;
    #pragma unroll
    for (int nt = 0; nt < 8; ++nt)
      #pragma unroll
      for (int r = 0; r < 4; ++r){
        int rel = koff + nt*16 + 4*g + r;
        float s = (rel >= -128 && rel <= 127) ? st[nt][r] * SCL : -1e30f;
        st[nt][r] = s;
        mx = fmaxf(mx, s);
      }
    mx = fmaxf(mx, __shfl_xor(mx, 16));
    mx = fmaxf(mx, __shfl_xor(mx, 32));
    float mnew = fmaxf(m_run, mx);
    float fac = __builtin_amdgcn_exp2f(m_run - mnew);
    m_run = mnew;
    float rs = 0.f;
    #pragma unroll
    for (int nt = 0; nt < 8; ++nt)
      #pragma unroll
      for (int r = 0; r < 4; ++r){
        float p = __builtin_amdgcn_exp2f(st[nt][r] - mnew);
        st[nt][r] = p; rs += p;
      }
    rs += __shfl_xor(rs, 16);
    rs += __shfl_xor(rs, 32);
    l_run = l_run * fac + rs;
    #pragma unroll
    for (int r = 0; r < 4; ++r){
      float fr = __shfl(fac, g*20 + r);
      #pragma unroll
      for (int dn = 0; dn < 4; ++dn) oacc[dn][r] *= fr;
    }

    #pragma unroll
    for (int nt = 0; nt < 8; ++nt){
      u32 plo, phi;
      asm volatile("v_cvt_pk_bf16_f32 %0, %1, %2" : "=v"(plo) : "v"(st[nt][0]), "v"(st[nt][1]));
      asm volatile("v_cvt_pk_bf16_f32 %0, %1, %2" : "=v"(phi) : "v"(st[nt][2]), "v"(st[nt][3]));
      u32x2 pv = { plo, phi };
      int byt = prow*256 + ((nt*32 + g*8) ^ ((c & 7) << 4));
      *(u32x2*)((char*)lP + byt) = pv;
    }

    __builtin_amdgcn_s_setprio(1);
    #pragma unroll
    for (int kt = 0; kt < 4; ++kt){
      short8 pa = *(const short8*)((char*)lP + prow*256 + ((kt*64 + g*16) ^ ((c & 7) << 4)));
      #pragma unroll
      for (int dn = 0; dn < 4; ++dn){
        int dd = dn*16 + c;
        short8 vb = *(const short8*)((char*)lVT + dd*256 + ((kt*64 + g*16) ^ ((c & 7) << 4)));
        oacc[dn] = MFMA16(pa, vb, oacc[dn]);
      }
    }
    __builtin_amdgcn_s_setprio(0);
    __syncthreads();
  }

  #pragma unroll
  for (int r = 0; r < 4; ++r){
    float li = __shfl(l_run, g*20 + r);
    float inv = 1.0f / li;
    size_t orow = ((size_t)(b*8192 + n*128 + w*16 + 4*g + r))*512 + h*64 + c;
    #pragma unroll
    for (int dn = 0; dn < 4; ++dn)
      Og[orow + dn*16] = f2bf(oacc[dn][r] * inv);
  }
}

extern "C" void kernel_launch(void* const* d_in, const int* in_sizes, int n_in,
                              void* d_out, int out_size, void* d_ws, size_t ws_size,
                              hipStream_t stream) {
  const float* inq  = (const float*)d_in[0];
  const float* inkv = (const float*)d_in[1];
  const float* Wq   = (const float*)d_in[2];
  const float* bq   = (const float*)d_in[3];
  const float* Wk   = (const float*)d_in[4];
  const float* bk   = (const float*)d_in[5];
  const float* Wv   = (const float*)d_in[6];
  const float* bv   = (const float*)d_in[7];
  const float* Wo   = (const float*)d_in[8];
  const float* bo   = (const float*)d_in[9];

  // workspace layout (bytes); total 82 MB
  char* ws = (char*)d_ws;
  u16* Xq  = (u16*)(ws + 0);                       // 16 MB  [16384,512] bf16
  u16* Xkv = (u16*)(ws + ((size_t)16 << 20));      // 16 MB
  u16* qb  = (u16*)(ws + ((size_t)32 << 20));      // 16 MB [B,H,S,D]
  u16* kbf = (u16*)(ws + ((size_t)48 << 20));      // 16 MB [B,H,S,D]
  u16* vT  = (u16*)(ws + ((size_t)64 << 20));      // 16 MB [B*H,D,S]
  u16* wT  = (u16*)(ws + ((size_t)80 << 20));      // 2 MB   4x [512,512] bf16 (transposed)
  u16* ob  = (u16*)(ws + 0);                       // reuse Xq slot (dead after gemm_qkv)

  cvtw<<<17408, 256, 0, stream>>>(inq, inkv, Wq, Wk, Wv, Wo, Xq, Xkv, wT);

  gemm_qkv<<<1536, 256, 0, stream>>>(Xq, Xkv, wT, bq, bk, bv, qb, kbf, vT);

  attn8<<<1024, 512, 0, stream>>>(qb, kbf, vT, ob);

  gemm_out<<<512, 256, 0, stream>>>(ob, wT + 3*262144, bo, (float*)d_out);
}

// Round 8
// 96.980 us; speedup vs baseline: 1.1079x; 1.0530x over previous
//
#include <hip/hip_runtime.h>

typedef unsigned short u16;
typedef unsigned int u32;
typedef __attribute__((ext_vector_type(8))) short short8;
typedef __attribute__((ext_vector_type(4))) float f32x4;
typedef __attribute__((ext_vector_type(4))) unsigned short u16x4;
typedef __attribute__((ext_vector_type(2))) unsigned int u32x2;

#define MFMA16(a,b,c) __builtin_amdgcn_mfma_f32_16x16x32_bf16((a),(b),(c),0,0,0)
#define AS3(p) ((__attribute__((address_space(3))) void*)(p))
#define AS1(p) ((const __attribute__((address_space(1))) void*)(p))

__device__ __forceinline__ u16 f2bf(float x){
  union { float f; unsigned u; } un; un.f = x;
  unsigned r = un.u + 0x7fffu + ((un.u >> 16) & 1u);
  return (u16)(r >> 16);
}

// ---------------- weight transpose+convert: out[n][k] = in[k][n], 512x512 ----------------
__global__ __launch_bounds__(256) void wtrans(const float* __restrict__ W0, const float* __restrict__ W1,
                                              const float* __restrict__ W2, const float* __restrict__ W3,
                                              u16* __restrict__ out){
  __shared__ float tile[32][33];
  const float* src = (blockIdx.z == 0) ? W0 : (blockIdx.z == 1) ? W1 : (blockIdx.z == 2) ? W2 : W3;
  u16* dst = out + (size_t)blockIdx.z * 262144;
  int k0 = blockIdx.x * 32, n0 = blockIdx.y * 32;
  int tx = threadIdx.x, ty = threadIdx.y;
  #pragma unroll
  for (int i = 0; i < 4; ++i)
    tile[ty + 8*i][tx] = src[(size_t)(k0 + ty + 8*i)*512 + n0 + tx];
  __syncthreads();
  #pragma unroll
  for (int i = 0; i < 4; ++i)
    dst[(size_t)(n0 + ty + 8*i)*512 + k0 + tx] = f2bf(tile[tx][ty + 8*i]);
}

// ---------------- shared GEMM core (ring-3 async staging, counted vmcnt) ----------------
// LDS bytes: A bufs 0..24576 (3 x 8KB), B bufs 24576..49152 (3 x 8KB). Rows 64 B, 16B chunks
// XOR-swizzled by ((row>>1)&3)<<4 (B via pre-swizzled global source; AF32-A via swizzled ds_write).
// AF32: A is f32, reg-staged 2-deep (arA/arB) + cvt_pk + ds_write.  !AF32: A bf16 via global_load_lds.
// MODE 0: bf16 out -> [B,H,S,D]; MODE 2: bf16 out -> vT[(b*512+col)*8192+s]; MODE 1: f32 row-major.
template<int MODE, bool AF32>
__device__ __forceinline__ void gemm_core(u16* sm, const void* Aptr, const u16* __restrict__ BT,
                                          const float* __restrict__ bias,
                                          u16* __restrict__ outb, float* __restrict__ outf,
                                          int bm, int bn){
  const int tid = threadIdx.x, lane = tid & 63, w = tid >> 6;
  const int g = lane >> 4, c = lane & 15;
  const int wm = (w >> 1) * 64, wn = (w & 1) * 64;
  const float* Af = (const float*)Aptr;
  const u16*  Ab = (const u16*)Aptr;
  f32x4 acc[4][4];
  #pragma unroll
  for (int mi = 0; mi < 4; ++mi)
    #pragma unroll
    for (int ni = 0; ni < 4; ++ni){ f32x4 z = {0.f,0.f,0.f,0.f}; acc[mi][ni] = z; }

  f32x4 arA[4], arB[4];

  auto issueA = [&](int kt, f32x4 (&ar)[4]){
    #pragma unroll
    for (int p = 0; p < 4; ++p){
      int row = p*32 + (tid >> 3);
      ar[p] = *(const f32x4*)(Af + (size_t)(bm*128 + row)*512 + kt*32 + (tid & 7)*4);
    }
  };
  auto writeA = [&](int buf, const f32x4 (&ar)[4]){
    #pragma unroll
    for (int p = 0; p < 4; ++p){
      int row = p*32 + (tid >> 3);
      u32 lo, hi;
      asm volatile("v_cvt_pk_bf16_f32 %0, %1, %2" : "=v"(lo) : "v"(ar[p][0]), "v"(ar[p][1]));
      asm volatile("v_cvt_pk_bf16_f32 %0, %1, %2" : "=v"(hi) : "v"(ar[p][2]), "v"(ar[p][3]));
      u32x2 pk = { lo, hi };
      int byt = buf*8192 + row*64 + (((tid & 7)*8) ^ (((row >> 1) & 3) << 4));
      *(u32x2*)((char*)sm + byt) = pk;
    }
  };
  auto stageA = [&](int buf, int kt){
    #pragma unroll
    for (int j = 0; j < 2; ++j){
      int lrow = 32*w + 16*j;
      int row = lrow + (lane >> 2), f = (row >> 1) & 3;
      const u16* ga = Ab + (size_t)(bm*128 + row)*512 + kt*32 + ((lane & 3) ^ f)*8;
      __builtin_amdgcn_global_load_lds(AS1(ga), AS3(sm + buf*4096 + lrow*32), 16, 0, 0);
    }
  };
  auto stageB = [&](int buf, int kt){
    #pragma unroll
    for (int j = 0; j < 2; ++j){
      int lrow = 32*w + 16*j;
      int row = lrow + (lane >> 2), f = (row >> 1) & 3;
      const u16* gb = BT + (size_t)(bn*128 + row)*512 + kt*32 + ((lane & 3) ^ f)*8;
      __builtin_amdgcn_global_load_lds(AS1(gb), AS3(sm + 12288 + buf*4096 + lrow*32), 16, 0, 0);
    }
  };
  auto compute = [&](int buf){
    short8 af[4], bfv[4];
    #pragma unroll
    for (int i = 0; i < 4; ++i){
      int ra = wm + 16*i + c;
      af[i]  = *(const short8*)((char*)sm + buf*8192 + ra*64 + ((g*16) ^ (((ra >> 1) & 3) << 4)));
      int rb = wn + 16*i + c;
      bfv[i] = *(const short8*)((char*)sm + 24576 + buf*8192 + rb*64 + ((g*16) ^ (((rb >> 1) & 3) << 4)));
    }
    #pragma unroll
    for (int mi = 0; mi < 4; ++mi)
      #pragma unroll
      for (int ni = 0; ni < 4; ++ni)
        acc[mi][ni] = MFMA16(af[mi], bfv[ni], acc[mi][ni]);
  };

  if constexpr (AF32){
    // 2-deep register A-pipeline + ring-3 LDS; fully unrolled so the compiler's
    // vmcnt scoreboard is exact (no loop-carried conservatism).
    issueA(0, arA); issueA(1, arB);
    stageB(0, 0); stageB(1, 1);
    writeA(0, arA);                    // compiler auto-drains A0 only
    #pragma unroll
    for (int kt = 0; kt < 16; kt += 2){
      // half 1: entry queue [B(kt), A(kt+1), B(kt+1)] (kt=0: [A1,B0,B1])
      if (kt == 0){ asm volatile("s_waitcnt vmcnt(4)" ::: "memory"); }
      else        { asm volatile("s_waitcnt vmcnt(8)" ::: "memory"); }
      asm volatile("s_waitcnt lgkmcnt(0)" ::: "memory");
      __builtin_amdgcn_sched_barrier(0);
      __builtin_amdgcn_s_barrier();
      __builtin_amdgcn_sched_barrier(0);
      if (kt < 14){ issueA(kt + 2, arA); stageB((kt + 2) % 3, kt + 2); }
      writeA((kt + 1) % 3, arB);
      compute(kt % 3);
      // half 2
      if (kt < 14){ asm volatile("s_waitcnt vmcnt(8)" ::: "memory"); }
      else        { asm volatile("s_waitcnt vmcnt(0)" ::: "memory"); }
      asm volatile("s_waitcnt lgkmcnt(0)" ::: "memory");
      __builtin_amdgcn_sched_barrier(0);
      __builtin_amdgcn_s_barrier();
      __builtin_amdgcn_sched_barrier(0);
      if (kt < 13){ issueA(kt + 3, arB); stageB((kt + 3) % 3, kt + 3); }
      if (kt < 14) writeA((kt + 2) % 3, arA);
      compute((kt + 1) % 3);
    }
  } else {
    stageA(0, 0); stageB(0, 0);
    stageA(1, 1); stageB(1, 1);
    int b0 = 0;
    for (int kt = 0; kt < 16; ++kt){
      if (kt == 15) { asm volatile("s_waitcnt vmcnt(0)" ::: "memory"); }
      else          { asm volatile("s_waitcnt vmcnt(4)" ::: "memory"); }
      __builtin_amdgcn_sched_barrier(0);
      __builtin_amdgcn_s_barrier();
      __builtin_amdgcn_sched_barrier(0);
      if (kt < 14){
        int b2 = b0 + 2; if (b2 >= 3) b2 -= 3;
        stageA(b2, kt + 2); stageB(b2, kt + 2);
      }
      compute(b0);
      b0 = (b0 == 2) ? 0 : b0 + 1;
    }
  }
  __syncthreads();   // staging dead; sm reused as epilogue repack tile

  const int lane3 = tid & 7;
  if (MODE == 0){
    #pragma unroll
    for (int mi = 0; mi < 4; ++mi)
      #pragma unroll
      for (int ni = 0; ni < 4; ++ni){
        int colL = wn + 16*ni + c;
        float bv = bias[bn*128 + colL];
        #pragma unroll
        for (int r = 0; r < 4; ++r){
          int rowL = wm + 16*mi + 4*g + r;
          int byt = rowL*256 + ((colL*2) ^ ((rowL & 7) << 4));
          *(u16*)((char*)sm + byt) = f2bf(acc[mi][ni][r] + bv);
        }
      }
    __syncthreads();
    #pragma unroll
    for (int p = 0; p < 8; ++p){
      int rh = (tid >> 3) + p*32;
      int rowL = rh >> 1, half = rh & 1;
      int byt = rowL*256 + ((half*128 + lane3*16) ^ ((rowL & 7) << 4));
      short8 vdat = *(const short8*)((char*)sm + byt);
      int rowG = bm*128 + rowL;
      int bb = rowG >> 13, s = rowG & 8191;
      int hh = bn*2 + half;
      *(short8*)(outb + (((size_t)(bb*8 + hh)*8192 + s) << 6) + lane3*8) = vdat;
    }
  } else if (MODE == 2){
    #pragma unroll
    for (int mi = 0; mi < 4; ++mi)
      #pragma unroll
      for (int ni = 0; ni < 4; ++ni){
        int colL = wn + 16*ni + c;
        float bv = bias[bn*128 + colL];
        u16x4 pk = { f2bf(acc[mi][ni][0] + bv), f2bf(acc[mi][ni][1] + bv),
                     f2bf(acc[mi][ni][2] + bv), f2bf(acc[mi][ni][3] + bv) };
        int row0 = wm + 16*mi + 4*g;
        int byt = colL*256 + ((row0*2) ^ ((colL & 7) << 4));
        *(u16x4*)((char*)sm + byt) = pk;
      }
    __syncthreads();
    #pragma unroll
    for (int p = 0; p < 8; ++p){
      int rh = (tid >> 3) + p*32;
      int colL = rh >> 1, half = rh & 1;
      int byt = colL*256 + ((half*128 + lane3*16) ^ ((colL & 7) << 4));
      short8 vdat = *(const short8*)((char*)sm + byt);
      int rowG0 = bm*128 + half*64 + lane3*8;
      int bb = rowG0 >> 13, s = rowG0 & 8191;
      int colG = bn*128 + colL;
      *(short8*)(outb + (((size_t)(bb*512 + colG)) << 13) + s) = vdat;
    }
  } else {
    float* smf = (float*)sm;
    #pragma unroll
    for (int hh = 0; hh < 2; ++hh){
      if ((w >> 1) == hh){
        #pragma unroll
        for (int mi = 0; mi < 4; ++mi)
          #pragma unroll
          for (int ni = 0; ni < 4; ++ni){
            int colL = wn + 16*ni + c;
            float bv = bias[bn*128 + colL];
            #pragma unroll
            for (int r = 0; r < 4; ++r){
              int rowh = 16*mi + 4*g + r;
              int byt = rowh*512 + ((colL*4) ^ (((rowh >> 2) & 7) << 4));
              *(float*)((char*)smf + byt) = acc[mi][ni][r] + bv;
            }
          }
      }
      __syncthreads();
      #pragma unroll
      for (int p = 0; p < 8; ++p){
        int idx = p*256 + tid;
        int row = idx >> 5, chunk = idx & 31;
        int byt = row*512 + ((chunk*16) ^ (((row >> 2) & 7) << 4));
        f32x4 vdat = *(const f32x4*)((char*)smf + byt);
        *(f32x4*)(outf + (size_t)(bm*128 + hh*64 + row)*512 + bn*128 + chunk*4) = vdat;
      }
      __syncthreads();
    }
  }
}

// merged QKV projection (f32 A direct, fused convert), 1D grid 1536, XCD-chunked
__global__ __launch_bounds__(256, 3) void gemm_qkv(const float* __restrict__ Xq, const float* __restrict__ Xkv,
                                                   const u16* __restrict__ wT,
                                                   const float* __restrict__ bq, const float* __restrict__ bk,
                                                   const float* __restrict__ bv,
                                                   u16* __restrict__ qb, u16* __restrict__ kbf, u16* __restrict__ vT){
  __shared__ u16 sm[24576];
  int bi = blockIdx.x;
  int orig = (bi & 7)*192 + (bi >> 3);
  int bm = orig / 12, bn = orig % 12;
  int which = bn >> 2, bnn = bn & 3;
  const float* A = which ? Xkv : Xq;
  const u16* BT = wT + which*262144;
  const float* bias = (which == 0) ? bq : (which == 1) ? bk : bv;
  if (which == 2) gemm_core<2, true>(sm, A, BT, bias, vT, nullptr, bm, bnn);
  else            gemm_core<0, true>(sm, A, BT, bias, (which == 0) ? qb : kbf, nullptr, bm, bnn);
}

// output projection: 1D grid 512, XCD-chunked; bf16 A, f32 out
__global__ __launch_bounds__(256, 3) void gemm_out(const u16* __restrict__ A, const u16* __restrict__ BT,
                                                   const float* __restrict__ bias, float* __restrict__ outf){
  __shared__ u16 sm[24576];
  int bi = blockIdx.x;
  int orig = (bi & 7)*64 + (bi >> 3);
  int bm = orig >> 2, bn = orig & 3;
  gemm_core<1, false>(sm, A, BT, bias, nullptr, outf, bm, bn);
}

// ---------------- banded flash attention, 8 waves x 16 q-rows ----------------
__global__ __launch_bounds__(512, 4) void attn8(const u16* __restrict__ Qg, const u16* __restrict__ Kg,
                                                const u16* __restrict__ VTg, u16* __restrict__ Og){
  __shared__ u16 lK[128*64];
  __shared__ u16 lVT[64*128];
  __shared__ u16 lP[128*128];
  const int tid = threadIdx.x, lane = tid & 63, w = tid >> 6;
  const int g = lane >> 4, c = lane & 15;
  int bi = blockIdx.x;
  int orig = (bi & 7)*128 + (bi >> 3);
  const int n = orig & 63, h = (orig >> 6) & 7, b = orig >> 9;
  const size_t baseq = ((size_t)(b*8 + h)) << 19;
  const size_t basev = ((size_t)((b*8 + h)*64)) << 13;

  short8 qf0, qf1;
  {
    const u16* qp = Qg + baseq + (size_t)(n*128 + w*16 + c)*64 + g*8;
    qf0 = *(const short8*)qp;
    qf1 = *(const short8*)(qp + 32);
  }

  float m_run = -1e30f, l_run = 0.f;
  f32x4 oacc[4];
  #pragma unroll
  for (int dn = 0; dn < 4; ++dn){ f32x4 z = {0.f,0.f,0.f,0.f}; oacc[dn] = z; }

  const int lo = (n == 0) ? 1 : 0;
  const int hi = (n == 63) ? 1 : 2;

  const int sr = tid >> 2, sq = tid & 3;
  const int vd = tid >> 3, vc = tid & 7;

  short8 kr0, kr1, vr0, vr1;
  {
    int kstart = n*128 + (lo - 1)*128;
    const u16* kp = Kg + baseq + (size_t)(kstart + sr)*64 + sq*16;
    kr0 = *(const short8*)kp; kr1 = *(const short8*)(kp + 8);
    const u16* vp = VTg + basev + ((size_t)vd << 13) + kstart + vc*16;
    vr0 = *(const short8*)vp; vr1 = *(const short8*)(vp + 8);
  }

  const int prow = w*16 + c;
  const float SCL = 0.125f * 1.44269504f;

  for (int kb = lo; kb <= hi; ++kb){
    {
      int byt = sr*128 + ((sq*32) ^ ((sr & 7) << 4));
      *(short8*)((char*)lK + byt) = kr0;
      byt = sr*128 + ((sq*32 + 16) ^ ((sr & 7) << 4));
      *(short8*)((char*)lK + byt) = kr1;
      int byt2 = vd*256 + ((vc*32) ^ ((vd & 7) << 4));
      *(short8*)((char*)lVT + byt2) = vr0;
      byt2 = vd*256 + ((vc*32 + 16) ^ ((vd & 7) << 4));
      *(short8*)((char*)lVT + byt2) = vr1;
    }
    __syncthreads();

    if (kb < hi){
      int kstart = n*128 + kb*128;
      const u16* kp = Kg + baseq + (size_t)(kstart + sr)*64 + sq*16;
      kr0 = *(const short8*)kp; kr1 = *(const short8*)(kp + 8);
      const u16* vp = VTg + basev + ((size_t)vd << 13) + kstart + vc*16;
      vr0 = *(const short8*)vp; vr1 = *(const short8*)(vp + 8);
    }

    f32x4 st[8];
    #pragma unroll
    for (int nt = 0; nt < 8; ++nt){ f32x4 z = {0.f,0.f,0.f,0.f}; st[nt] = z; }
    __builtin_amdgcn_s_setprio(1);
    #pragma unroll
    for (int nt = 0; nt < 8; ++nt){
      int row = nt*16 + c;
      int swz = (row & 7) << 4;
      short8 kf0 = *(const short8*)((char*)lK + row*128 + ((g*16) ^ swz));
      short8 kf1 = *(const short8*)((char*)lK + row*128 + ((64 + g*16) ^ swz));
      st[nt] = MFMA16(kf0, qf0, st[nt]);
      st[nt] = MFMA16(kf1, qf1, st[nt]);
    }
    __builtin_amdgcn_s_setprio(0);

    int koff = (kb - 1)*128 - (w*16 + c);
    float mx = -1e30f;
    #pragma unroll
    for (int nt = 0; nt < 8; ++nt)
      #pragma unroll
      for (int r = 0; r < 4; ++r){
        int rel = koff + nt*16 + 4*g + r;
        float s = (rel >= -128 && rel <= 127) ? st[nt][r] * SCL : -1e30f;
        st[nt][r] = s;
        mx = fmaxf(mx, s);
      }
    mx = fmaxf(mx, __shfl_xor(mx, 16));
    mx = fmaxf(mx, __shfl_xor(mx, 32));
    float mnew = fmaxf(m_run, mx);
    float fac = __builtin_amdgcn_exp2f(m_run - mnew);
    m_run = mnew;
    float rs = 0.f;
    #pragma unroll
    for (int nt = 0; nt < 8; ++nt)
      #pragma unroll
      for (int r = 0; r < 4; ++r){
        float p = __builtin_amdgcn_exp2f(st[nt][r] - mnew);
        st[nt][r] = p; rs += p;
      }
    rs += __shfl_xor(rs, 16);
    rs += __shfl_xor(rs, 32);
    l_run = l_run * fac + rs;
    #pragma unroll
    for (int r = 0; r < 4; ++r){
      float fr = __shfl(fac, g*20 + r);
      #pragma unroll
      for (int dn = 0; dn < 4; ++dn) oacc[dn][r] *= fr;
    }

    #pragma unroll
    for (int nt = 0; nt < 8; ++nt){
      u32 plo, phi;
      asm volatile("v_cvt_pk_bf16_f32 %0, %1, %2" : "=v"(plo) : "v"(st[nt][0]), "v"(st[nt][1]));
      asm volatile("v_cvt_pk_bf16_f32 %0, %1, %2" : "=v"(phi) : "v"(st[nt][2]), "v"(st[nt][3]));
      u32x2 pv = { plo, phi };
      int byt = prow*256 + ((nt*32 + g*8) ^ ((c & 7) << 4));
      *(u32x2*)((char*)lP + byt) = pv;
    }

    __builtin_amdgcn_s_setprio(1);
    #pragma unroll
    for (int kt = 0; kt < 4; ++kt){
      short8 pa = *(const short8*)((char*)lP + prow*256 + ((kt*64 + g*16) ^ ((c & 7) << 4)));
      #pragma unroll
      for (int dn = 0; dn < 4; ++dn){
        int dd = dn*16 + c;
        short8 vb = *(const short8*)((char*)lVT + dd*256 + ((kt*64 + g*16) ^ ((c & 7) << 4)));
        oacc[dn] = MFMA16(pa, vb, oacc[dn]);
      }
    }
    __builtin_amdgcn_s_setprio(0);
    __syncthreads();
  }

  #pragma unroll
  for (int r = 0; r < 4; ++r){
    float li = __shfl(l_run, g*20 + r);
    float inv = 1.0f / li;
    size_t orow = ((size_t)(b*8192 + n*128 + w*16 + 4*g + r))*512 + h*64 + c;
    #pragma unroll
    for (int dn = 0; dn < 4; ++dn)
      Og[orow + dn*16] = f2bf(oacc[dn][r] * inv);
  }
}

extern "C" void kernel_launch(void* const* d_in, const int* in_sizes, int n_in,
                              void* d_out, int out_size, void* d_ws, size_t ws_size,
                              hipStream_t stream) {
  const float* inq  = (const float*)d_in[0];
  const float* inkv = (const float*)d_in[1];
  const float* Wq   = (const float*)d_in[2];
  const float* bq   = (const float*)d_in[3];
  const float* Wk   = (const float*)d_in[4];
  const float* bk   = (const float*)d_in[5];
  const float* Wv   = (const float*)d_in[6];
  const float* bv   = (const float*)d_in[7];
  const float* Wo   = (const float*)d_in[8];
  const float* bo   = (const float*)d_in[9];

  char* ws = (char*)d_ws;
  u16* qb  = (u16*)(ws + 0);                       // 16 MB [B,H,S,D]
  u16* kbf = (u16*)(ws + ((size_t)16 << 20));      // 16 MB [B,H,S,D]
  u16* vT  = (u16*)(ws + ((size_t)32 << 20));      // 16 MB [B*H,D,S]
  u16* ob  = (u16*)(ws + ((size_t)48 << 20));      // 16 MB [B,S,512]
  u16* wT  = (u16*)(ws + ((size_t)64 << 20));      // 2 MB

  wtrans<<<dim3(16,16,4), dim3(32,8), 0, stream>>>(Wq, Wk, Wv, Wo, wT);

  gemm_qkv<<<1536, 256, 0, stream>>>(inq, inkv, wT, bq, bk, bv, qb, kbf, vT);

  attn8<<<1024, 512, 0, stream>>>(qb, kbf, vT, ob);

  gemm_out<<<512, 256, 0, stream>>>(ob, wT + 3*262144, bo, (float*)d_out);
}